// Round 4
// baseline (195.388 us; speedup 1.0000x reference)
//
#include <hip/hip_runtime.h>

// MSE_DQ_FK: dual-quaternion denorm -> local rot -> FK -> mse losses -> scalar.
// B=64, T=1024, J=22, C=176. Layout (B,C,T), T contiguous -> thread-per-t
// gives coalesced 256B/wave loads. Only rotation quats (4 of 8 dq channels)
// are read. Telescoping identity: global rot[j] = conj(q0n) * qjn (local[0]
// forced identity + unit-norm cancellation); ik/dec roots are identity.
//
// Round-6 structure: ROLE SPLIT BY BLOCKIDX (256-thread blocks).
//   Evidence so far:
//   - R1/R2: role-split inside a 512-thread block -> allocator clamps to
//     128 VGPR regardless of launch_bounds min-waves arg -> 44MB scratch
//     spill, 57us.
//   - R3: chain-split 256-thread blocks -> VGPR=92, spill gone (WRITE=80KB),
//     but 2.3x total loads + 10 tiny waves/SIMD run serially -> still 56us.
//     Both HBM-fed and L3-resident replays took 56us -> latency-bound,
//     NOT bandwidth-bound.
//   Fix: role-split across BLOCKS (256-thread blocks don't clamp VGPR):
//     blocks 0..255   (role 0): {ik, tgt} -> EE losses (joints 4,8,13,17,21)
//     blocks 256..511 (role 1): {dec, ik} -> REG losses (16 non-sparse)
//   Same pose-range blocks (bid, bid+256) are congruent mod 8 -> same XCD
//   -> ik double-read shared in that XCD's L2. 512 blocks = 2 blocks/CU =
//   8 waves/CU = 2 waves/SIMD; each wave keeps the deep per-chain prefetch
//   pipeline (R0's ILP) while the second wave covers the other's stalls.
//  * UNIT-QUAT FROBENIUS IDENTITY: ||R(a)-R(b)||_F^2 = 8*(1 - dot(a,b)^2)
//    for unit quats -> replaces 2x qmat + 27-op diff (~90 VALU) with ~10.

#define T_DIM 1024

struct Q { float w, x, y, z; };
struct V3 { float x, y, z; };
struct St { Q rot; V3 pos; };

__device__ __forceinline__ Q qmul(const Q a, const Q b) {
    Q r;
    r.w = a.w*b.w - a.x*b.x - a.y*b.y - a.z*b.z;
    r.x = a.w*b.x + a.x*b.w + a.y*b.z - a.z*b.y;
    r.y = a.w*b.y - a.x*b.z + a.y*b.w + a.z*b.x;
    r.z = a.w*b.z + a.x*b.y - a.y*b.x + a.z*b.w;
    return r;
}

__device__ __forceinline__ V3 qrot(const Q q, const V3 v) {
    float tx = 2.f*(q.y*v.z - q.z*v.y);
    float ty = 2.f*(q.z*v.x - q.x*v.z);
    float tz = 2.f*(q.x*v.y - q.y*v.x);
    V3 r;
    r.x = v.x + q.w*tx + (q.y*tz - q.z*ty);
    r.y = v.y + q.w*ty + (q.z*tx - q.x*tz);
    r.z = v.z + q.w*tz + (q.x*ty - q.y*tx);
    return r;
}

// ||R(a)-R(b)||_F^2 for UNIT quaternions:
//   = 6 - 2*tr(R(a)^T R(b)) = 6 - 2*(4*dot(a,b)^2 - 1) = 8*(1 - dot(a,b)^2)
__device__ __forceinline__ float rmdiff2u(const Q a, const Q b) {
    float d = a.w*b.w + a.x*b.x + a.y*b.y + a.z*b.z;
    return 8.f*(1.f - d*d);
}

__device__ __forceinline__ float pdiff2(const V3 a, const V3 b) {
    float dx=a.x-b.x, dy=a.y-b.y, dz=a.z-b.z;
    return dx*dx+dy*dy+dz*dz;
}

__device__ __forceinline__ V3 v3add(const V3 a, const V3 b) {
    return V3{a.x+b.x, a.y+b.y, a.z+b.z};
}

// Denorm raw quat channels (c0..c0+3) then normalize. mean/stdv indexed with
// compile-time-uniform c0 -> scalar loads.
__device__ __forceinline__ Q mkq(const float r[4], const int c0,
                                 const float* __restrict__ mean,
                                 const float* __restrict__ stdv) {
    Q q;
    q.w = r[0]*stdv[c0+0] + mean[c0+0];
    q.x = r[1]*stdv[c0+1] + mean[c0+1];
    q.y = r[2]*stdv[c0+2] + mean[c0+2];
    q.z = r[3]*stdv[c0+3] + mean[c0+3];
    float inv = rsqrtf(q.w*q.w + q.x*q.x + q.y*q.y + q.z*q.z);
    q.w*=inv; q.x*=inv; q.y*=inv; q.z*=inv;
    return q;
}

// Prefetch raw channel dwords for joints J0..J0+N-1 (two streams) into
// register arrays. 8 loads/joint; chains are 4-5 joints -> 32-40 outstanding.
// Both pointers are pre-adjusted so channel base is j*8 uniformly (ik stream
// pointer is shifted by -8*T_DIM to account for its missing root joint).
template<int J0, int N>
__device__ __forceinline__ void pf2(
    const float* __restrict__ xp, const float* __restrict__ yp,
    float (*xr)[4], float (*yr)[4])
{
#pragma unroll
    for (int jj = 0; jj < N; ++jj) {
        const int j = J0 + jj;
#pragma unroll
        for (int c = 0; c < 4; ++c) {
            xr[jj][c] = xp[(j*8 + c)*T_DIM];
            yr[jj][c] = yp[(j*8 + c)*T_DIM];
        }
    }
}

// One joint step for both chains from prefetched raw data.
// PRE: premultiply Y's quat by q0c (tgt stream: non-identity root).
// LOSS: accumulate pos/rot losses at this joint.
template<int J, bool LOSS, bool PRE>
__device__ __forceinline__ void step2(
    St& sx, St& sy,
    const float xr[4], const float yr[4],
    const float* __restrict__ mean, const float* __restrict__ stdv,
    const float* __restrict__ offs, const Q q0c,
    float& ap, float& ar)
{
    const int c0 = J*8;
    Q qx = mkq(xr, c0, mean, stdv);
    Q qy = mkq(yr, c0, mean, stdv);
    if (PRE) qy = qmul(q0c, qy);
    V3 off = { offs[3*J], offs[3*J+1], offs[3*J+2] };
    V3 px = v3add(qrot(sx.rot, off), sx.pos);
    V3 py = v3add(qrot(sy.rot, off), sy.pos);
    if (LOSS) {
        ap += pdiff2(px, py);
        ar += rmdiff2u(qx, qy);
    }
    sx.rot = qx; sx.pos = px;
    sy.rot = qy; sy.pos = py;
}

// Walk all 5 chains for one stream pair with pipelined prefetch.
// EEROLE=true : X=ik, Y=tgt (PRE), losses at EE joints {4,8,13,17,21}
// EEROLE=false: X=dec, Y=ik, losses at the 16 non-sparse joints
template<bool EEROLE>
__device__ __forceinline__ void walk(
    const float* __restrict__ xp, const float* __restrict__ yp,
    const float* __restrict__ mean, const float* __restrict__ stdv,
    const float* __restrict__ offs,
    float& ap, float& ar)
{
    // PARENTS = [0,0,1,2,3, 0,5,6,7, 0,9,10,11,12, 11,14,15,16, 11,18,19,20]
    // Chains: A=1..4(EE4) B=5..8(EE8) C=9..13(EE13,branch@11) D=14..17(EE17)
    //         E=18..21(EE21)
    float Xa[4][4], Ya[4][4];
    float Xb[4][4], Yb[4][4];
    float Xc[5][4], Yc[5][4];
    float Xd[4][4], Yd[4][4];
    float Xe[4][4], Ye[4][4];
    float rq0[4];

    if (EEROLE) {
#pragma unroll
        for (int c = 0; c < 4; ++c) rq0[c] = yp[c*T_DIM];  // tgt root quat
    }
    pf2<1,4>(xp, yp, Xa, Ya);
    pf2<5,4>(xp, yp, Xb, Yb);

    Q q0c = {1.f, 0.f, 0.f, 0.f};
    if (EEROLE) {
        Q q0 = mkq(rq0, 0, mean, stdv);
        q0c = { q0.w, -q0.x, -q0.y, -q0.z };
    }
    const St root = { {1.f,0.f,0.f,0.f}, {0.f,0.f,0.f} };
    St sx, sy;

    // chain A
    sx = root; sy = root;
    step2<1, !EEROLE, EEROLE>(sx,sy, Xa[0],Ya[0], mean,stdv,offs,q0c, ap,ar);
    step2<2, !EEROLE, EEROLE>(sx,sy, Xa[1],Ya[1], mean,stdv,offs,q0c, ap,ar);
    step2<3, !EEROLE, EEROLE>(sx,sy, Xa[2],Ya[2], mean,stdv,offs,q0c, ap,ar);
    step2<4,  EEROLE, EEROLE>(sx,sy, Xa[3],Ya[3], mean,stdv,offs,q0c, ap,ar);

    pf2<9,5>(xp, yp, Xc, Yc);

    // chain B
    sx = root; sy = root;
    step2<5, !EEROLE, EEROLE>(sx,sy, Xb[0],Yb[0], mean,stdv,offs,q0c, ap,ar);
    step2<6, !EEROLE, EEROLE>(sx,sy, Xb[1],Yb[1], mean,stdv,offs,q0c, ap,ar);
    step2<7, !EEROLE, EEROLE>(sx,sy, Xb[2],Yb[2], mean,stdv,offs,q0c, ap,ar);
    step2<8,  EEROLE, EEROLE>(sx,sy, Xb[3],Yb[3], mean,stdv,offs,q0c, ap,ar);

    pf2<14,4>(xp, yp, Xd, Yd);

    // chain C: 9-10-11 (branch point 11), then 12-13
    sx = root; sy = root;
    step2<9,  !EEROLE, EEROLE>(sx,sy, Xc[0],Yc[0], mean,stdv,offs,q0c, ap,ar);
    step2<10, !EEROLE, EEROLE>(sx,sy, Xc[1],Yc[1], mean,stdv,offs,q0c, ap,ar);
    step2<11, !EEROLE, EEROLE>(sx,sy, Xc[2],Yc[2], mean,stdv,offs,q0c, ap,ar);
    const St sx11 = sx, sy11 = sy;
    step2<12, !EEROLE, EEROLE>(sx,sy, Xc[3],Yc[3], mean,stdv,offs,q0c, ap,ar);
    step2<13,  EEROLE, EEROLE>(sx,sy, Xc[4],Yc[4], mean,stdv,offs,q0c, ap,ar);

    pf2<18,4>(xp, yp, Xe, Ye);

    // chain D: 14-17 from branch point
    sx = sx11; sy = sy11;
    step2<14, !EEROLE, EEROLE>(sx,sy, Xd[0],Yd[0], mean,stdv,offs,q0c, ap,ar);
    step2<15, !EEROLE, EEROLE>(sx,sy, Xd[1],Yd[1], mean,stdv,offs,q0c, ap,ar);
    step2<16, !EEROLE, EEROLE>(sx,sy, Xd[2],Yd[2], mean,stdv,offs,q0c, ap,ar);
    step2<17,  EEROLE, EEROLE>(sx,sy, Xd[3],Yd[3], mean,stdv,offs,q0c, ap,ar);

    // chain E: 18-21 from branch point
    sx = sx11; sy = sy11;
    step2<18, !EEROLE, EEROLE>(sx,sy, Xe[0],Ye[0], mean,stdv,offs,q0c, ap,ar);
    step2<19, !EEROLE, EEROLE>(sx,sy, Xe[1],Ye[1], mean,stdv,offs,q0c, ap,ar);
    step2<20, !EEROLE, EEROLE>(sx,sy, Xe[2],Ye[2], mean,stdv,offs,q0c, ap,ar);
    step2<21,  EEROLE, EEROLE>(sx,sy, Xe[3],Ye[3], mean,stdv,offs,q0c, ap,ar);
}

__global__ __launch_bounds__(256, 2) void fk_loss_kernel(
    const float* __restrict__ ik, const float* __restrict__ dec,
    const float* __restrict__ tgt, const float* __restrict__ mean,
    const float* __restrict__ stdv, const float* __restrict__ offs,
    float* __restrict__ out)
{
    __shared__ float swred[4];
    const int tid = threadIdx.x;
    const int bid = blockIdx.x;
    // role by block: bids 0..255 = EE, 256..511 = REG. bid and bid+256 are
    // congruent mod 8 -> same XCD (HW round-robins blockIdx across XCDs),
    // so both roles' ik reads share that XCD's L2.
    const int role = bid >> 8;
    const int pose_blk = bid & 255;

    const int p = pose_blk * 256 + tid;
    const int b = p >> 10;           // / T
    const int t = p & 1023;          // % T
    // ik pointer pre-shifted by -8*T_DIM: its array lacks the root joint, so
    // channel base becomes j*8 uniformly (only dereferenced for j >= 1).
    const float* ikp = ik  + (size_t)b * (168*1024) + t - (size_t)(8*T_DIM);
    const float* dep = dec + (size_t)b * (176*1024) + t;
    const float* tgp = tgt + (size_t)b * (176*1024) + t;

    float ap = 0.f, ar = 0.f;
    float loss;
    const float BT = 65536.f;
    if (role == 0) {
        // loss_ee = ee_pos/(B*T*5*3) + ee_rm/(B*T*5*9)
        walk<true>(ikp, tgp, mean, stdv, offs, ap, ar);
        loss = ap * (1.0f/(BT*15.f)) + ar * (1.0f/(BT*45.f));
    } else {
        // loss_reg = 0.1*( reg_pos/(B*T*16*3) + reg_rm/(B*T*16*9) )
        walk<false>(dep, ikp, mean, stdv, offs, ap, ar);
        loss = ap * (0.1f/(BT*48.f)) + ar * (0.1f/(BT*144.f));
    }

    // wave(64) shuffle reduce -> cross-wave via LDS -> one atomic per block
#pragma unroll
    for (int o = 32; o > 0; o >>= 1) loss += __shfl_down(loss, o);
    if ((tid & 63) == 0) swred[tid >> 6] = loss;
    __syncthreads();
    if (tid == 0) {
        atomicAdd(out, swred[0]+swred[1]+swred[2]+swred[3]);
    }
}

extern "C" void kernel_launch(void* const* d_in, const int* in_sizes, int n_in,
                              void* d_out, int out_size, void* d_ws, size_t ws_size,
                              hipStream_t stream) {
    // inputs (setup_inputs order): input(unused), input_ik, input_decoder,
    // target, mean_dqs, std_dqs, offsets
    const float* ikx  = (const float*)d_in[1];
    const float* dec  = (const float*)d_in[2];
    const float* tgt  = (const float*)d_in[3];
    const float* mean = (const float*)d_in[4];
    const float* stdv = (const float*)d_in[5];
    const float* offs = (const float*)d_in[6];
    float* out = (float*)d_out;

    hipMemsetAsync(out, 0, sizeof(float), stream);
    // 256 pose-blocks x 2 roles = 512 blocks of 256 threads
    // (2 blocks/CU at <=256 VGPR -> 8 waves/CU = 2 waves/SIMD)
    fk_loss_kernel<<<512, 256, 0, stream>>>(ikx, dec, tgt, mean, stdv, offs, out);
}

// Round 5
// 181.914 us; speedup vs baseline: 1.0741x; 1.0741x over previous
//
#include <hip/hip_runtime.h>

// MSE_DQ_FK: dual-quaternion denorm -> local rot -> FK -> mse losses -> scalar.
// B=64, T=1024, J=22, C=176. Layout (B,C,T), T contiguous. Only rotation
// quats (4 of 8 dq channels) are read. Telescoping identity: global rot[j] =
// conj(q0n)*qjn; ik/dec roots are identity.
//
// Round-7 structure: FLOAT2 POSE-PAIR + ROLE SPLIT BY BLOCK.
//   Cross-round evidence:
//   - per-CU vector-load-instruction count tracks dispatch time ~linearly
//     (R0: 1040 instrs -> <40us; R1/R2/R4: 1376 -> 57us; R3: 1840 -> 56us);
//     L3-resident replays = HBM replays (56us both, R3) and VALUBusy 12-19%
//     -> the limiter is per-CU vmem instruction/miss-handling throughput,
//     not BW/VALU/latency.
//   - the allocator pins 512-thread and launch_bounds'd 256-thread blocks
//     at 128 VGPR (R1/R2/R4 all spilled 44MB); R3 shows small working sets
//     get what they need. So: shrink demand below 128, don't fight the cap.
//   Design: one thread = one POSE PAIR (t, t+1), all loads float2 -> same
//   bytes, HALF the load instructions. Role split by block keeps full CU
//   coverage: 128 pose-blocks x 2 roles = 256 blocks x 256 threads.
//     role 0: {ik, tgt} -> EE losses (joints 4,8,13,17,21)
//     role 1: {dec, ik} -> REG losses (16 non-sparse joints)
//   Per-CU load instrs: 688 (0.5x of R4, 0.66x of R0). Pose-pair doubles
//   per-wave ILP (two independent FK chains interleaved).
//   Register discipline (target <=~120, under the 128 cap BY DESIGN):
//   - single-buffered prefetch batches: A=4,B=4 joints, C=3+2, D/E=2+2
//   - base addresses computed from blockIdx ONLY (provably wave-uniform ->
//     SGPR base + small VGPR offset; no per-load 64-bit VGPR address pairs)
//  * UNIT-QUAT FROBENIUS IDENTITY: ||R(a)-R(b)||_F^2 = 8*(1 - dot(a,b)^2).

#define T_DIM 1024

struct alignas(8) F2 { float u, v; };

__device__ __forceinline__ F2 operator+(F2 a, F2 b){ return {a.u+b.u, a.v+b.v}; }
__device__ __forceinline__ F2 operator-(F2 a, F2 b){ return {a.u-b.u, a.v-b.v}; }
__device__ __forceinline__ F2 operator*(F2 a, F2 b){ return {a.u*b.u, a.v*b.v}; }
__device__ __forceinline__ F2 operator*(F2 a, float s){ return {a.u*s, a.v*s}; }
__device__ __forceinline__ F2 operator+(F2 a, float s){ return {a.u+s, a.v+s}; }
__device__ __forceinline__ F2 f2neg(F2 a){ return {-a.u, -a.v}; }
__device__ __forceinline__ F2 f2bc(float s){ return {s, s}; }
__device__ __forceinline__ F2 f2rsq(F2 a){ return {rsqrtf(a.u), rsqrtf(a.v)}; }

struct Q2 { F2 w, x, y, z; };
struct V2 { F2 x, y, z; };
struct St2 { Q2 rot; V2 pos; };

__device__ __forceinline__ Q2 qmul2(const Q2 a, const Q2 b) {
    Q2 r;
    r.w = a.w*b.w - a.x*b.x - a.y*b.y - a.z*b.z;
    r.x = a.w*b.x + a.x*b.w + a.y*b.z - a.z*b.y;
    r.y = a.w*b.y - a.x*b.z + a.y*b.w + a.z*b.x;
    r.z = a.w*b.z + a.x*b.y - a.y*b.x + a.z*b.w;
    return r;
}

// rotate the CONSTANT offset vector (ox,oy,oz) by quat pair q
__device__ __forceinline__ V2 qrot2(const Q2 q, float ox, float oy, float oz) {
    F2 tx = (q.y*oz - q.z*oy)*2.f;
    F2 ty = (q.z*ox - q.x*oz)*2.f;
    F2 tz = (q.x*oy - q.y*ox)*2.f;
    V2 r;
    r.x = (q.w*tx + (q.y*tz - q.z*ty)) + ox;
    r.y = (q.w*ty + (q.z*tx - q.x*tz)) + oy;
    r.z = (q.w*tz + (q.x*ty - q.y*tx)) + oz;
    return r;
}

// ||R(a)-R(b)||_F^2 for UNIT quats = 8*(1 - dot(a,b)^2)
__device__ __forceinline__ F2 rmdiff2u(const Q2 a, const Q2 b) {
    F2 d = a.w*b.w + a.x*b.x + a.y*b.y + a.z*b.z;
    return (f2bc(1.f) - d*d)*8.f;
}

__device__ __forceinline__ F2 pdiff2(const V2 a, const V2 b) {
    F2 dx = a.x-b.x, dy = a.y-b.y, dz = a.z-b.z;
    return dx*dx + dy*dy + dz*dz;
}

// Denorm raw quat channels then normalize. c0 is a literal after unroll ->
// mean/stdv become scalar loads.
__device__ __forceinline__ Q2 mkq2(const F2 r[4], const int c0,
                                   const float* __restrict__ mean,
                                   const float* __restrict__ stdv) {
    Q2 q;
    q.w = r[0]*stdv[c0+0] + mean[c0+0];
    q.x = r[1]*stdv[c0+1] + mean[c0+1];
    q.y = r[2]*stdv[c0+2] + mean[c0+2];
    q.z = r[3]*stdv[c0+3] + mean[c0+3];
    F2 inv = f2rsq(q.w*q.w + q.x*q.x + q.y*q.y + q.z*q.z);
    q.w = q.w*inv; q.x = q.x*inv; q.y = q.y*inv; q.z = q.z*inv;
    return q;
}

// float2 load at uniform base + (literal channel + per-thread t0) offset.
__device__ __forceinline__ F2 ld2(const float* __restrict__ base, int idx) {
    return *reinterpret_cast<const F2*>(base + idx);
}

// Load raw quat channels for joints J0..J0+N-1, both streams, pose pair.
// ik base is pre-shifted by -8*T_DIM (its array lacks the root joint).
template<int J0, int N>
__device__ __forceinline__ void ldb(
    const float* __restrict__ xp, const float* __restrict__ yp, const int t0,
    F2 (*X)[4], F2 (*Y)[4])
{
#pragma unroll
    for (int jj = 0; jj < N; ++jj) {
#pragma unroll
        for (int c = 0; c < 4; ++c) {
            X[jj][c] = ld2(xp, ((J0+jj)*8 + c)*T_DIM + t0);
            Y[jj][c] = ld2(yp, ((J0+jj)*8 + c)*T_DIM + t0);
        }
    }
}

// One joint step for both streams, pose pair.
template<int J, bool LOSS, bool PRE>
__device__ __forceinline__ void stepf(
    St2& sx, St2& sy,
    const F2 xr[4], const F2 yr[4],
    const float* __restrict__ mean, const float* __restrict__ stdv,
    const float* __restrict__ offs, const Q2& q0c,
    F2& ap, F2& ar)
{
    const int c0 = J*8;
    Q2 qx = mkq2(xr, c0, mean, stdv);
    Q2 qy = mkq2(yr, c0, mean, stdv);
    if (PRE) qy = qmul2(q0c, qy);
    const float ox = offs[3*J], oy = offs[3*J+1], oz = offs[3*J+2];
    V2 dx = qrot2(sx.rot, ox, oy, oz);
    V2 dy = qrot2(sy.rot, ox, oy, oz);
    V2 px = { dx.x + sx.pos.x, dx.y + sx.pos.y, dx.z + sx.pos.z };
    V2 py = { dy.x + sy.pos.x, dy.y + sy.pos.y, dy.z + sy.pos.z };
    if (LOSS) {
        ap = ap + pdiff2(px, py);
        ar = ar + rmdiff2u(qx, qy);
    }
    sx.rot = qx; sx.pos = px;
    sy.rot = qy; sy.pos = py;
}

// Walk all 5 chains, single-buffered small batches (register discipline).
// EEROLE=true : X=ik, Y=tgt (root premult), loss at chain ends {4,8,13,17,21}
// EEROLE=false: X=dec, Y=ik, loss at the 16 non-sparse (interior) joints
template<bool EEROLE>
__device__ __forceinline__ void walk(
    const float* __restrict__ xp, const float* __restrict__ yp, const int t0,
    const float* __restrict__ mean, const float* __restrict__ stdv,
    const float* __restrict__ offs, F2& ap, F2& ar)
{
    // PARENTS = [0,0,1,2,3, 0,5,6,7, 0,9,10,11,12, 11,14,15,16, 11,18,19,20]
    F2 X[4][4], Y[4][4];
    F2 rq0[4];

    if (EEROLE) {
#pragma unroll
        for (int c = 0; c < 4; ++c) rq0[c] = ld2(yp, c*T_DIM + t0);
    }
    ldb<1,4>(xp, yp, t0, X, Y);          // chain A raw

    Q2 q0c = { f2bc(1.f), f2bc(0.f), f2bc(0.f), f2bc(0.f) };
    if (EEROLE) {
        Q2 q0 = mkq2(rq0, 0, mean, stdv);
        q0c = { q0.w, f2neg(q0.x), f2neg(q0.y), f2neg(q0.z) };
    }
    const St2 root = { { f2bc(1.f), f2bc(0.f), f2bc(0.f), f2bc(0.f) },
                       { f2bc(0.f), f2bc(0.f), f2bc(0.f) } };
    St2 sx, sy;

    // chain A: 1..4 (EE 4)
    sx = root; sy = root;
    stepf<1, !EEROLE, EEROLE>(sx,sy, X[0],Y[0], mean,stdv,offs,q0c, ap,ar);
    stepf<2, !EEROLE, EEROLE>(sx,sy, X[1],Y[1], mean,stdv,offs,q0c, ap,ar);
    stepf<3, !EEROLE, EEROLE>(sx,sy, X[2],Y[2], mean,stdv,offs,q0c, ap,ar);
    stepf<4,  EEROLE, EEROLE>(sx,sy, X[3],Y[3], mean,stdv,offs,q0c, ap,ar);

    // chain B: 5..8 (EE 8)
    ldb<5,4>(xp, yp, t0, X, Y);
    sx = root; sy = root;
    stepf<5, !EEROLE, EEROLE>(sx,sy, X[0],Y[0], mean,stdv,offs,q0c, ap,ar);
    stepf<6, !EEROLE, EEROLE>(sx,sy, X[1],Y[1], mean,stdv,offs,q0c, ap,ar);
    stepf<7, !EEROLE, EEROLE>(sx,sy, X[2],Y[2], mean,stdv,offs,q0c, ap,ar);
    stepf<8,  EEROLE, EEROLE>(sx,sy, X[3],Y[3], mean,stdv,offs,q0c, ap,ar);

    // chain C: 9,10,11 (branch @11), then 12,13 (EE 13)
    ldb<9,3>(xp, yp, t0, X, Y);
    sx = root; sy = root;
    stepf<9,  !EEROLE, EEROLE>(sx,sy, X[0],Y[0], mean,stdv,offs,q0c, ap,ar);
    stepf<10, !EEROLE, EEROLE>(sx,sy, X[1],Y[1], mean,stdv,offs,q0c, ap,ar);
    stepf<11, !EEROLE, EEROLE>(sx,sy, X[2],Y[2], mean,stdv,offs,q0c, ap,ar);
    const St2 sx11 = sx, sy11 = sy;
    ldb<12,2>(xp, yp, t0, X, Y);
    stepf<12, !EEROLE, EEROLE>(sx,sy, X[0],Y[0], mean,stdv,offs,q0c, ap,ar);
    stepf<13,  EEROLE, EEROLE>(sx,sy, X[1],Y[1], mean,stdv,offs,q0c, ap,ar);

    // chain D: 14..17 from branch point (EE 17)
    ldb<14,2>(xp, yp, t0, X, Y);
    sx = sx11; sy = sy11;
    stepf<14, !EEROLE, EEROLE>(sx,sy, X[0],Y[0], mean,stdv,offs,q0c, ap,ar);
    stepf<15, !EEROLE, EEROLE>(sx,sy, X[1],Y[1], mean,stdv,offs,q0c, ap,ar);
    ldb<16,2>(xp, yp, t0, X, Y);
    stepf<16, !EEROLE, EEROLE>(sx,sy, X[0],Y[0], mean,stdv,offs,q0c, ap,ar);
    stepf<17,  EEROLE, EEROLE>(sx,sy, X[1],Y[1], mean,stdv,offs,q0c, ap,ar);

    // chain E: 18..21 from branch point (EE 21)
    ldb<18,2>(xp, yp, t0, X, Y);
    sx = sx11; sy = sy11;
    stepf<18, !EEROLE, EEROLE>(sx,sy, X[0],Y[0], mean,stdv,offs,q0c, ap,ar);
    stepf<19, !EEROLE, EEROLE>(sx,sy, X[1],Y[1], mean,stdv,offs,q0c, ap,ar);
    ldb<20,2>(xp, yp, t0, X, Y);
    stepf<20, !EEROLE, EEROLE>(sx,sy, X[0],Y[0], mean,stdv,offs,q0c, ap,ar);
    stepf<21,  EEROLE, EEROLE>(sx,sy, X[1],Y[1], mean,stdv,offs,q0c, ap,ar);
}

__global__ __launch_bounds__(256) void fk_loss_kernel(
    const float* __restrict__ ik, const float* __restrict__ dec,
    const float* __restrict__ tgt, const float* __restrict__ mean,
    const float* __restrict__ stdv, const float* __restrict__ offs,
    float* __restrict__ out)
{
    __shared__ float swred[4];
    const int tid = threadIdx.x;
    const int bid = blockIdx.x;
    // 128 pose-blocks x 2 roles = 256 blocks. bid and bid+128 are congruent
    // mod 8 -> same XCD -> role 1's ik re-read hits that XCD's L2.
    const int role = bid >> 7;
    const int pb   = bid & 127;          // pose block: 512 poses
    const int bb   = pb >> 1;            // batch index b (BLOCK-UNIFORM)
    const int t0   = (pb & 1)*512 + 2*tid;   // even; pose pair (t0, t0+1)

    // bases are blockIdx-derived only -> provably wave-uniform -> SGPR base
    // + per-thread VGPR offset addressing (no 64-bit VGPR address pairs).
    // ik base pre-shifted by -8*T_DIM (array lacks root joint; j>=1 always).
    const float* ikp = ik  + (size_t)bb * (168*1024) - (size_t)(8*T_DIM);
    const float* dep = dec + (size_t)bb * (176*1024);
    const float* tgp = tgt + (size_t)bb * (176*1024);

    F2 ap = f2bc(0.f), ar = f2bc(0.f);
    float loss;
    const float BT = 65536.f;
    if (role == 0) {
        // loss_ee = ee_pos/(B*T*5*3) + ee_rm/(B*T*5*9)
        walk<true>(ikp, tgp, t0, mean, stdv, offs, ap, ar);
        loss = (ap.u + ap.v) * (1.0f/(BT*15.f))
             + (ar.u + ar.v) * (1.0f/(BT*45.f));
    } else {
        // loss_reg = 0.1*( reg_pos/(B*T*16*3) + reg_rm/(B*T*16*9) )
        walk<false>(dep, ikp, t0, mean, stdv, offs, ap, ar);
        loss = (ap.u + ap.v) * (0.1f/(BT*48.f))
             + (ar.u + ar.v) * (0.1f/(BT*144.f));
    }

    // wave(64) shuffle reduce -> cross-wave via LDS -> one atomic per block
#pragma unroll
    for (int o = 32; o > 0; o >>= 1) loss += __shfl_down(loss, o);
    if ((tid & 63) == 0) swred[tid >> 6] = loss;
    __syncthreads();
    if (tid == 0) {
        atomicAdd(out, swred[0]+swred[1]+swred[2]+swred[3]);
    }
}

extern "C" void kernel_launch(void* const* d_in, const int* in_sizes, int n_in,
                              void* d_out, int out_size, void* d_ws, size_t ws_size,
                              hipStream_t stream) {
    // inputs (setup_inputs order): input(unused), input_ik, input_decoder,
    // target, mean_dqs, std_dqs, offsets
    const float* ikx  = (const float*)d_in[1];
    const float* dec  = (const float*)d_in[2];
    const float* tgt  = (const float*)d_in[3];
    const float* mean = (const float*)d_in[4];
    const float* stdv = (const float*)d_in[5];
    const float* offs = (const float*)d_in[6];
    float* out = (float*)d_out;

    hipMemsetAsync(out, 0, sizeof(float), stream);
    // 128 pose-blocks x 2 roles = 256 blocks of 256 threads (1 block/CU);
    // each thread carries a pose pair via float2 loads.
    fk_loss_kernel<<<256, 256, 0, stream>>>(ikx, dec, tgt, mean, stdv, offs, out);
}